// Round 3
// baseline (110.940 us; speedup 1.0000x reference)
//
#include <hip/hip_runtime.h>

// Problem constants (match reference)
#define BB 4096
#define DD 16
#define MM 4
#define RR 2048
#define CC 10
#define TB 4            // batch rows per block
#define RPT (RR / 256)  // rules per thread = 8

typedef __attribute__((ext_vector_type(4))) float f32x4;
typedef __attribute__((ext_vector_type(2))) float f32x2;

// ---------------- prep kernel ----------------
// wsumT2[c2][r] = (sum_j cons[r][j][2c2], sum_j cons[r][j][2c2+1])  (c-pairs, r-major)
// codes[r]     = packed 2-bit membership indices, byte g = dims 4g..4g+3
__global__ __launch_bounds__(256) void prep_kernel(
    const float* __restrict__ cons, const int* __restrict__ rules,
    f32x2* __restrict__ wsumT2, unsigned int* __restrict__ codes)
{
    int gid = blockIdx.x * 256 + threadIdx.x;
    if (gid < RR * 5) {
        int r = gid / 5, c2 = gid - r * 5;
        const float* cr = cons + (size_t)r * (DD + 1) * CC + 2 * c2;
        float s0 = 0.0f, s1 = 0.0f;
#pragma unroll
        for (int j = 0; j < DD + 1; ++j) { s0 += cr[j * CC]; s1 += cr[j * CC + 1]; }
        f32x2 v; v.x = s0; v.y = s1;
        wsumT2[c2 * RR + r] = v;
    }
    if (gid < RR) {
        const int* rrp = rules + gid * DD;
        unsigned int code = 0;
#pragma unroll
        for (int g = 0; g < 4; ++g) {
            unsigned int byt = 0;
#pragma unroll
            for (int k = 0; k < 4; ++k)
                byt |= (((unsigned int)rrp[g * 4 + k]) & 3u) << (2 * k);
            code |= byt << (8 * g);
        }
        codes[gid] = code;
    }
}

// ---------------- main kernel ----------------
// 256 threads / block, TB=4 batch rows, all 2048 rules.
// Row-interleaved LDS product tables (one ds_read_b128 serves 4 rows).
// VGPR discipline: no fs register file (re-gather in phase 4), unroll 1 on
// rule loops, launch_bounds(256,4) -> <=128 VGPR, 4 blocks/CU, zero tail.
__global__ __launch_bounds__(256, 4) void anfis_main(
    const float* __restrict__ x, const float* __restrict__ centers,
    const float* __restrict__ widths, const f32x2* __restrict__ wsumT2,
    const unsigned int* __restrict__ codes,
    float* __restrict__ out, float* __restrict__ norm_fs, float* __restrict__ x_ext)
{
    // QUAD4 (16 KB) and RED (10.9 KB) are barrier-separated -> alias
    __shared__ __align__(16) char pool[4 * 256 * sizeof(f32x4)];
    f32x4 (*QUAD4)[256] = (f32x4 (*)[256])pool;  // [g][e] -> rows
    float (*RED)[68]    = (float (*)[68])pool;   // [40][64+pad]

    __shared__ float MF[TB][64];       // [row][d*4+m]
    __shared__ f32x4 PAIR4[8][16];     // [p][i0+4*i1] -> rows
    __shared__ float xs[TB][DD];
    __shared__ float sx[TB];
    __shared__ float wpart[4][TB];
    __shared__ float invl[TB];
    __shared__ float oscale[TB];
    __shared__ float part2[TB * CC][4];

    const int tid = threadIdx.x;
    const int b0 = blockIdx.x * TB;
    const int lane = tid & 63;
    const int wv = tid >> 6;

    // ---- phase 1a: load x rows, emit x_ext ----
    if (tid < TB * DD) {
        int row = tid / DD, d = tid % DD;
        float v = x[(b0 + row) * DD + d];
        xs[row][d] = v;
        x_ext[(b0 + row) * (DD + 1) + d] = v;
    }
    if (tid < TB) x_ext[(b0 + tid) * (DD + 1) + DD] = 1.0f;
    __syncthreads();

    if (tid < TB) {
        float s = 1.0f;
#pragma unroll
        for (int d = 0; d < DD; ++d) s += xs[tid][d];
        sx[tid] = s;
    }

    // ---- phase 1b: membership values (4 rows x 64, one per thread) ----
    {
        int row = tid >> 6, dm = tid & 63, d = dm >> 2, m = dm & 3;
        float c = centers[d * MM + m];
        float w = widths[d * MM + m];
        float z = xs[row][d] - c;
        MF[row][dm] = expf(-(z * z) / (2.0f * w * w));
    }
    __syncthreads();

    // ---- phase 1c: pair tables, row-interleaved ----
    if (tid < 8 * 16) {
        int p = tid >> 4, e = tid & 15;
        int i0 = e & 3, i1 = e >> 2;
        f32x4 v;
#pragma unroll
        for (int row = 0; row < TB; ++row)
            v[row] = MF[row][(2 * p) * 4 + i0] * MF[row][(2 * p + 1) * 4 + i1];
        PAIR4[p][e] = v;
    }
    __syncthreads();

    // ---- phase 1d: quad tables, row-interleaved ----
#pragma unroll
    for (int i = tid; i < 4 * 256; i += 256) {
        int g = i >> 8, e = i & 255;
        QUAD4[g][e] = PAIR4[2 * g][e & 15] * PAIR4[2 * g + 1][e >> 4];
    }
    __syncthreads();

    // ---- phase 2: firing-strength row sums only ----
    unsigned int creg[RPT];
#pragma unroll
    for (int j = 0; j < RPT; ++j) creg[j] = codes[tid + 256 * j];

    float ssum[TB];
#pragma unroll
    for (int row = 0; row < TB; ++row) ssum[row] = 0.0f;

#pragma unroll 1
    for (int j = 0; j < RPT; ++j) {
        unsigned int code = creg[j];
        f32x4 q0 = QUAD4[0][code & 255u];
        f32x4 q1 = QUAD4[1][(code >> 8) & 255u];
        f32x4 q2 = QUAD4[2][(code >> 16) & 255u];
        f32x4 q3 = QUAD4[3][code >> 24];
        f32x4 p = (q0 * q1) * (q2 * q3);
#pragma unroll
        for (int row = 0; row < TB; ++row) ssum[row] += p[row];
    }

    // ---- phase 3: per-row fs total across block ----
#pragma unroll
    for (int row = 0; row < TB; ++row) {
        float s = ssum[row];
#pragma unroll
        for (int off = 32; off > 0; off >>= 1) s += __shfl_xor(s, off, 64);
        if (lane == 0) wpart[wv][row] = s;
    }
    __syncthreads();
    if (tid < TB) {
        float t = wpart[0][tid] + wpart[1][tid] + wpart[2][tid] + wpart[3][tid];
        float inv = 1.0f / (t + 1e-9f);
        invl[tid] = inv;
        oscale[tid] = sx[tid] * inv;
    }
    __syncthreads();

    // ---- phase 4: re-gather, write norm_fs, accumulate raw fs*Wsum ----
    float acc[TB][CC];
#pragma unroll
    for (int row = 0; row < TB; ++row)
#pragma unroll
        for (int c = 0; c < CC; ++c) acc[row][c] = 0.0f;

    const float inv0 = invl[0], inv1 = invl[1], inv2 = invl[2], inv3 = invl[3];

#pragma unroll 1
    for (int j = 0; j < RPT; ++j) {
        int r = tid + 256 * j;
        unsigned int code = creg[j];
        f32x2 w01 = wsumT2[0 * RR + r];
        f32x2 w23 = wsumT2[1 * RR + r];
        f32x2 w45 = wsumT2[2 * RR + r];
        f32x2 w67 = wsumT2[3 * RR + r];
        f32x2 w89 = wsumT2[4 * RR + r];
        f32x4 q0 = QUAD4[0][code & 255u];
        f32x4 q1 = QUAD4[1][(code >> 8) & 255u];
        f32x4 q2 = QUAD4[2][(code >> 16) & 255u];
        f32x4 q3 = QUAD4[3][code >> 24];
        f32x4 p = (q0 * q1) * (q2 * q3);

        norm_fs[(size_t)(b0 + 0) * RR + r] = p[0] * inv0;
        norm_fs[(size_t)(b0 + 1) * RR + r] = p[1] * inv1;
        norm_fs[(size_t)(b0 + 2) * RR + r] = p[2] * inv2;
        norm_fs[(size_t)(b0 + 3) * RR + r] = p[3] * inv3;

        float wc[CC] = {w01.x, w01.y, w23.x, w23.y, w45.x,
                        w45.y, w67.x, w67.y, w89.x, w89.y};
#pragma unroll
        for (int row = 0; row < TB; ++row)
#pragma unroll
            for (int c = 0; c < CC; ++c)
                acc[row][c] = fmaf(p[row], wc[c], acc[row][c]);
    }
    __syncthreads();  // all QUAD4 reads drained -> RED aliasing safe

    // ---- phase 5: reduce acc[row][c] across 256 threads ----
#pragma unroll
    for (int row = 0; row < TB; ++row) {
#pragma unroll
        for (int c = 0; c < CC; ++c) {
            float s = acc[row][c];
            s += __shfl_xor(s, 1, 64);
            s += __shfl_xor(s, 2, 64);
            if ((lane & 3) == 0) RED[row * CC + c][wv * 16 + (lane >> 2)] = s;
        }
    }
    __syncthreads();
    if (tid < 160) {
        int v = tid % 40, ch = tid / 40;
        float s = 0.0f;
        int base = ch * 16;
#pragma unroll
        for (int i = 0; i < 16; ++i) s += RED[v][base + i];
        part2[v][ch] = s;
    }
    __syncthreads();
    if (tid < TB * CC) {
        float val = part2[tid][0] + part2[tid][1] + part2[tid][2] + part2[tid][3];
        int row = tid / CC, c = tid % CC;
        out[(b0 + row) * CC + c] = oscale[row] * val;
    }
}

// ---------------- launch ----------------
extern "C" void kernel_launch(void* const* d_in, const int* in_sizes, int n_in,
                              void* d_out, int out_size, void* d_ws, size_t ws_size,
                              hipStream_t stream) {
    const float* x       = (const float*)d_in[0];
    const float* centers = (const float*)d_in[1];
    const float* widths  = (const float*)d_in[2];
    const float* cons    = (const float*)d_in[3];
    const int*   rules   = (const int*)d_in[4];

    float* out_p     = (float*)d_out;                       // (B, C)
    float* norm_fs_p = out_p + (size_t)BB * CC;             // (B, R)
    float* x_ext_p   = norm_fs_p + (size_t)BB * RR;         // (B, D+1)

    f32x2* wsumT2 = (f32x2*)d_ws;                           // 5*2048 float2 = 80 KB
    unsigned int* codes = (unsigned int*)((char*)d_ws + (size_t)5 * RR * sizeof(f32x2));

    prep_kernel<<<(RR * 5 + 255) / 256, 256, 0, stream>>>(cons, rules, wsumT2, codes);

    // MEASUREMENT ROUND: launch main TWICE (idempotent - reads only inputs/ws,
    // rewrites identical outputs). dur_R3 = ovh + prep + 2*main; next round
    // reverts to a single launch so main = dur_R3 - dur_R4 exactly.
    anfis_main<<<BB / TB, 256, 0, stream>>>(x, centers, widths, wsumT2, codes,
                                            out_p, norm_fs_p, x_ext_p);
    anfis_main<<<BB / TB, 256, 0, stream>>>(x, centers, widths, wsumT2, codes,
                                            out_p, norm_fs_p, x_ext_p);
}